// Round 7
// baseline (34.508 us; speedup 1.0000x reference)
//
#include <hip/hip_runtime.h>

// ---------------------------------------------------------------------------
// TimeLSTMCell fused kernel for MI355X (gfx950) — round 9
// B=4096, D=256, U=512; out = concat(h, c_m) fp32
//
// ROUND 9: 4 independent blocks/CU (the only untested direction).
//   r8 cooperative fusion never launched (silent failure under harness
//   capture). Data so far: 1 blk/CU < 2 blk/CU consistently (-1.8..-2.6us);
//   all throughput levers neutral -> exposed per-step latency in lockstep
//   barrier groups is the candidate binder. Test by DOUBLING the number of
//   independent barrier groups per CU:
//   - main: 64x32 output tile, BK=32, 4 waves (wm x wn = 2x2 of 32r x 16c),
//     acc 64 VGPR/thread, LDS 2 x 16KB = 32KB -> 4 blocks/CU (128KB, 16
//     waves/CU), __launch_bounds__(256,4). Grid (16,64) = 1024 blocks.
//     Counted-vmcnt 24-step loop (r6 scheme, L=[4 x8, 3 x16]).
//   - prep: BK=32 tiles: A 64x32 (xs,hs), B 160x32 (ksw) / 96x32 (rsw),
//     swizzle SWZ32 (4 chunks/row, XOR (r>>1)&3 -> 2-way bank alias = free).
//   - epilogue: t1_constraint = -1e-5 ALWAYS (sigmoid > -1e-5) -> drop the
//     per-element select.
//   Discriminator: per-CU staging volume rises ~78% (B re-read x2) while
//   concurrency doubles. Win => latency-bound confirmed; loss => staging-BW
//   bound; neutral => residual is prep+boundary+epilogue.
// ---------------------------------------------------------------------------

typedef __attribute__((ext_vector_type(8))) short short8_t;   // 8 bf16
typedef __attribute__((ext_vector_type(4))) float f32x4_t;
typedef unsigned int u32;

#define B_N 4096
#define D_K 256
#define U_N 512

__device__ __forceinline__ unsigned short f2bf(float f) {
    unsigned int x = __float_as_uint(f);
    unsigned int r = x + 0x7fffu + ((x >> 16) & 1u);   // RNE
    return (unsigned short)(r >> 16);
}

__device__ __forceinline__ float sigf(float z) {
    return 1.0f / (1.0f + __expf(-z));
}

// fast tanh: exact at +/-inf, ~1e-7 abs err
__device__ __forceinline__ float tanhfast(float z) {
    return 1.0f - 2.0f / (1.0f + __expf(2.0f * z));
}

__device__ __forceinline__ void gl16(const unsigned short* g, unsigned short* l) {
    __builtin_amdgcn_global_load_lds(
        (const __attribute__((address_space(1))) u32*)g,
        (__attribute__((address_space(3))) u32*)l, 16, 0, 0);
}

// BK=32 swizzled element offset of (row r, k-chunk kc), 4 chunks (16B) per row
// bank check (fragment read, lanes lr0..15 x lq0..3): byte = r*64 +
// (kc^((r>>1)&3))*16 -> row pairs share a 16B slot (2-way = free, m136),
// 8 slot-classes cover all 32 banks.
#define SWZ32(r, kc) ((((r) * 4) + ((kc) ^ (((r) >> 1) & 3))) * 8)

// counted vmcnt wait + scheduling fence (compile-time literal N)
#define WAIT_VM(N)                                            \
    asm volatile("s_waitcnt vmcnt(" #N ")" ::: "memory");     \
    __builtin_amdgcn_sched_barrier(0)

// ---------------------------------------------------------------------------
// prepass: BK=32 tiles, 4 segments by flat 16B-chunk id
//   xs : A tiles 64x32 (256 ch),  t = rb*8  + kb, rb 0..63, kb 0..7
//   hs : A tiles 64x32 (256 ch),  t = rb*16 + kb, rb 0..63, kb 0..15
//   ksw: B tiles 160x32 (640 ch), t = nb*8  + kb, nb 0..15, kb 0..7
//        row r = m*32 + cc (gate m 0..4, col-in-block cc 0..31)
//   rsw: B tiles  96x32 (384 ch), t = nb*16 + kb, nb 0..15, kb 0..15
// chunks: 131072 + 262144 + 81920 + 98304 = 573440 = 2240 blocks x 256
// ---------------------------------------------------------------------------
__global__ __launch_bounds__(256) void prep(
    const float* __restrict__ x, const float* __restrict__ h0,
    const float* __restrict__ kern, const float* __restrict__ rk,
    unsigned short* __restrict__ xs, unsigned short* __restrict__ hs,
    unsigned short* __restrict__ ksw, unsigned short* __restrict__ rsw)
{
    const int c = blockIdx.x * 256 + threadIdx.x;
    if (c < 131072) {                       // ---- x ----
        const int t = c >> 8, q = c & 255;
        const int row = q >> 2, kc = q & 3;
        const int rb = t >> 3, kb = t & 7;
        const float* s = x + (size_t)(rb * 64 + row) * D_K + kb * 32 + kc * 8;
        short8_t o;
#pragma unroll
        for (int j = 0; j < 8; ++j) o[j] = (short)f2bf(s[j]);
        *reinterpret_cast<short8_t*>(xs + (size_t)t * 2048 + SWZ32(row, kc)) = o;
    } else if (c < 393216) {                // ---- h0 ----
        const int c2 = c - 131072;
        const int t = c2 >> 8, q = c2 & 255;
        const int row = q >> 2, kc = q & 3;
        const int rb = t >> 4, kb = t & 15;
        const float* s = h0 + (size_t)(rb * 64 + row) * U_N + kb * 32 + kc * 8;
        short8_t o;
#pragma unroll
        for (int j = 0; j < 8; ++j) o[j] = (short)f2bf(s[j]);
        *reinterpret_cast<short8_t*>(hs + (size_t)t * 2048 + SWZ32(row, kc)) = o;
    } else if (c < 475136) {                // ---- kernel (transpose) ----
        const int c2 = c - 393216;
        const int t = c2 / 640, q = c2 - t * 640;
        const int kc = q / 160, r = q - kc * 160;     // r = m*32 + cc
        const int nb = t >> 3, kb = t & 7;
        const int col = (r >> 5) * U_N + nb * 32 + (r & 31);
        short8_t o;
#pragma unroll
        for (int j = 0; j < 8; ++j)
            o[j] = (short)f2bf(kern[(size_t)(kb * 32 + kc * 8 + j) * 2560 + col]);
        *reinterpret_cast<short8_t*>(ksw + (size_t)t * 5120 + SWZ32(r, kc)) = o;
    } else {                                // ---- rk (transpose) ----
        const int c2 = c - 475136;
        const int t = c2 / 384, q = c2 - t * 384;
        const int kc = q / 96, r = q - kc * 96;       // r = m*32 + cc
        const int nb = t >> 4, kb = t & 15;
        const int col = (r >> 5) * U_N + nb * 32 + (r & 31);
        short8_t o;
#pragma unroll
        for (int j = 0; j < 8; ++j)
            o[j] = (short)f2bf(rk[(size_t)(kb * 32 + kc * 8 + j) * 1536 + col]);
        *reinterpret_cast<short8_t*>(rsw + (size_t)t * 3072 + SWZ32(r, kc)) = o;
    }
}

// ---------------------------------------------------------------------------
// main fused kernel
// grid (16, 64) = 1024 blocks (4/CU), 256 threads (4 waves)
// wave (wm, wn) = (wave>>1, wave&1): rows [32*wm,+32) x cols [16*wn,+16)
// of the 64x32 band, for every stacked gate matrix.
// LDS buffer = A 4KB (2048 elems) + B 12KB (6144 elems, 640/384 chunks
// padded to 768/512 so every wave issues the same load count) = 16KB; x2.
// ---------------------------------------------------------------------------
__global__ __launch_bounds__(256, 4) void tlstm_main(
    const unsigned short* __restrict__ xs,    // swizzled x tiles
    const unsigned short* __restrict__ hs,    // swizzled h0 tiles
    const unsigned short* __restrict__ ksw,   // swizzled kernel^T tiles
    const unsigned short* __restrict__ rsw,   // swizzled rk^T tiles
    const float* __restrict__ tvec,           // [4096]
    const float* __restrict__ c0,             // [4096][512]
    const float* __restrict__ ktime,          // [1536] cols [t1,t2,o]
    float* __restrict__ out)                  // h, then c_m
{
    __shared__ __align__(16) unsigned short lds[2][8192];    // 32KB total

    const int tid = threadIdx.x;
    const int wave = tid >> 6;
    const int lane = tid & 63;
    const int lr = lane & 15;
    const int lq = lane >> 4;
    const int wm = wave >> 1;                 // 0..1 : 32-row half
    const int wn = wave & 1;                  // 0..1 : 16-col half
    const int nb = blockIdx.x;                // 0..15 (32-col blocks)
    const int rb = blockIdx.y;                // 0..63 (64-row blocks)

    // acc[m][p]: gate m (0..4 = x@K, 5..7 = h0@RK), row frag p (wm*32+p*16)
    f32x4_t acc[8][2];
#pragma unroll
    for (int m = 0; m < 8; ++m)
#pragma unroll
        for (int p = 0; p < 2; ++p)
            acc[m][p] = (f32x4_t){0.f, 0.f, 0.f, 0.f};

    // ---- staging: linear global_load_lds, wave-uniform LDS dest ----
    // per-thread vmem ops: phase1 (s<8): 1 A + 3 B = 4; phase2: 1 A + 2 B = 3
    // B chunk counts (640/384) padded to wave-uniform issue counts: the last
    // B load's upper waves re-read valid lower chunks into the LDS pad
    // (slots 640..767 / 384..511) — harmless, keeps vmcnt uniform.
    auto stage = [&](int s, int buf) {
        unsigned short* ab = &lds[buf][0];
        unsigned short* bb = &lds[buf][2048];
        if (s < 8) {
            const unsigned short* at = xs + (size_t)(rb * 8 + s) * 2048;
            gl16(at + (size_t)tid * 8, ab + (size_t)(wave * 64) * 8);
            const unsigned short* bt = ksw + (size_t)(nb * 8 + s) * 5120;
            gl16(bt + (size_t)tid * 8,                 bb + (size_t)(wave * 64) * 8);
            gl16(bt + (size_t)(256 + tid) * 8,         bb + (size_t)(256 + wave * 64) * 8);
            gl16(bt + (size_t)(512 + (tid & 127)) * 8, bb + (size_t)(512 + wave * 64) * 8);
        } else {
            const unsigned short* at = hs + (size_t)(rb * 16 + (s - 8)) * 2048;
            gl16(at + (size_t)tid * 8, ab + (size_t)(wave * 64) * 8);
            const unsigned short* bt = rsw + (size_t)(nb * 16 + (s - 8)) * 3072;
            gl16(bt + (size_t)tid * 8,                 bb + (size_t)(wave * 64) * 8);
            gl16(bt + (size_t)(256 + (tid & 127)) * 8, bb + (size_t)(256 + wave * 64) * 8);
        }
    };

    auto compute1 = [&](int buf) {      // x @ kernel -> acc[0..4]
        const unsigned short* ab = &lds[buf][0];
        const unsigned short* bb = &lds[buf][2048];
        short8_t a0 = *reinterpret_cast<const short8_t*>(ab + SWZ32(wm * 32 + lr, lq));
        short8_t a1 = *reinterpret_cast<const short8_t*>(ab + SWZ32(wm * 32 + 16 + lr, lq));
#pragma unroll
        for (int m = 0; m < 5; ++m) {
            const int r = m * 32 + wn * 16 + lr;
            short8_t b = *reinterpret_cast<const short8_t*>(bb + SWZ32(r, lq));
            acc[m][0] = __builtin_amdgcn_mfma_f32_16x16x32_bf16(a0, b, acc[m][0], 0, 0, 0);
            acc[m][1] = __builtin_amdgcn_mfma_f32_16x16x32_bf16(a1, b, acc[m][1], 0, 0, 0);
        }
    };

    auto compute2 = [&](int buf) {      // h0 @ rk -> acc[5..7]
        const unsigned short* ab = &lds[buf][0];
        const unsigned short* bb = &lds[buf][2048];
        short8_t a0 = *reinterpret_cast<const short8_t*>(ab + SWZ32(wm * 32 + lr, lq));
        short8_t a1 = *reinterpret_cast<const short8_t*>(ab + SWZ32(wm * 32 + 16 + lr, lq));
#pragma unroll
        for (int m = 0; m < 3; ++m) {
            const int r = m * 32 + wn * 16 + lr;
            short8_t b = *reinterpret_cast<const short8_t*>(bb + SWZ32(r, lq));
            acc[5 + m][0] = __builtin_amdgcn_mfma_f32_16x16x32_bf16(a0, b, acc[5 + m][0], 0, 0, 0);
            acc[5 + m][1] = __builtin_amdgcn_mfma_f32_16x16x32_bf16(a1, b, acc[5 + m][1], 0, 0, 0);
        }
    };

    // step body for tile S: wait until tile S's loads landed (leave the NV
    // just-issued loads of tile S+1 in flight), sync, compute, sync.
#define K_BODY(S, NV, CF)                                  \
    {                                                      \
        WAIT_VM(NV);                                       \
        __builtin_amdgcn_s_barrier();                      \
        __builtin_amdgcn_sched_barrier(0);                 \
        CF((S) & 1);                                       \
        __builtin_amdgcn_sched_barrier(0);                 \
        __builtin_amdgcn_s_barrier();                      \
        __builtin_amdgcn_sched_barrier(0);                 \
    }

    // ---- counted-vmcnt pipelined K-loop: 24 steps, L = [4 x8, 3 x16] ----
    stage(0, 0);
    stage(1, 1);   K_BODY(0, 4, compute1);
    stage(2, 0);   K_BODY(1, 4, compute1);
    stage(3, 1);   K_BODY(2, 4, compute1);
    stage(4, 0);   K_BODY(3, 4, compute1);
    stage(5, 1);   K_BODY(4, 4, compute1);
    stage(6, 0);   K_BODY(5, 4, compute1);
    stage(7, 1);   K_BODY(6, 4, compute1);
    stage(8, 0);   K_BODY(7, 3, compute1);
    stage(9, 1);   K_BODY(8, 3, compute2);
    stage(10, 0);  K_BODY(9, 3, compute2);
    stage(11, 1);  K_BODY(10, 3, compute2);
    stage(12, 0);  K_BODY(11, 3, compute2);
    stage(13, 1);  K_BODY(12, 3, compute2);
    stage(14, 0);  K_BODY(13, 3, compute2);
    stage(15, 1);  K_BODY(14, 3, compute2);
    stage(16, 0);  K_BODY(15, 3, compute2);
    stage(17, 1);  K_BODY(16, 3, compute2);
    stage(18, 0);  K_BODY(17, 3, compute2);
    stage(19, 1);  K_BODY(18, 3, compute2);
    stage(20, 0);  K_BODY(19, 3, compute2);
    stage(21, 1);  K_BODY(20, 3, compute2);
    stage(22, 0);  K_BODY(21, 3, compute2);
    stage(23, 1);  K_BODY(22, 3, compute2);
    K_BODY(23, 0, compute2);

    // ---- epilogue: TimeLSTM elementwise (fp32) ----
    // t1_constraint: sigmoid output is always > -1e-5, so the reference's
    // where() always selects the constant -1e-5.
    const float NEG_EPS = -1e-5f;
    const int u = nb * 32 + wn * 16 + lr;
    const float kt1 = ktime[u];
    const float kt2 = ktime[U_N + u];
    const float kto = ktime[2 * U_N + u];
#pragma unroll
    for (int p = 0; p < 2; ++p)
#pragma unroll
        for (int i2 = 0; i2 < 4; ++i2) {
            const int b = rb * 64 + wm * 32 + p * 16 + lq * 4 + i2;
            const float tb = tvec[b];
            const float c0v = c0[(size_t)b * U_N + u];
            const float x_i  = acc[0][p][i2];
            const float x_c  = acc[1][p][i2];
            const float x_o  = acc[2][p][i2];
            const float x_t1 = acc[3][p][i2];
            const float x_t2 = acc[4][p][i2];
            const float r_i  = acc[5][p][i2];
            const float r_c  = acc[6][p][i2];
            const float r_o  = acc[7][p][i2];

            const float ig  = sigf(x_i + r_i);
            const float t1v = sigf(x_t1 + sigf(tb * kt1));
            const float t2v = sigf(x_t2 + sigf(tb * kt2));
            const float ct  = tanhfast(x_c + r_c);
            const float cm_ = (1.f - ig * t1v) * c0v + ig * ct * NEG_EPS;
            const float cm  = (1.f - ig) * c0v + ig * ct * t2v;
            const float og  = sigf(x_o + r_o + tb * kto);

            out[(size_t)b * U_N + u] = tanhfast(cm_) * og;
            out[(size_t)B_N * U_N + (size_t)b * U_N + u] = cm;
        }
}

// ---------------------------------------------------------------------------
extern "C" void kernel_launch(void* const* d_in, const int* in_sizes, int n_in,
                              void* d_out, int out_size, void* d_ws, size_t ws_size,
                              hipStream_t stream) {
    const float* x     = (const float*)d_in[0];   // [4096][256]
    const float* t     = (const float*)d_in[1];   // [4096][1]
    const float* h0    = (const float*)d_in[2];   // [4096][512]
    const float* c0    = (const float*)d_in[3];   // [4096][512]
    const float* kern  = (const float*)d_in[4];   // [256][2560]
    const float* rk    = (const float*)d_in[5];   // [512][1536]
    const float* ktime = (const float*)d_in[6];   // [1][1536]
    float* out = (float*)d_out;

    // ws layout (bytes):
    //   xs  @ 0        : 4096*256*2  = 2,097,152  (swizzled 64x32 tiles)
    //   hs  @ 2097152  : 4096*512*2  = 4,194,304
    //   ksw @ 6291456  : 2560*256*2  = 1,310,720  (swizzled 160x32 tiles)
    //   rsw @ 7602176  : 1536*512*2  = 1,572,864  (swizzled  96x32 tiles)
    unsigned short* xs  = (unsigned short*)d_ws;
    unsigned short* hs  = (unsigned short*)((char*)d_ws + 2097152);
    unsigned short* ksw = (unsigned short*)((char*)d_ws + 6291456);
    unsigned short* rsw = (unsigned short*)((char*)d_ws + 7602176);

    prep<<<2240, 256, 0, stream>>>(x, h0, kern, rk, xs, hs, ksw, rsw);
    tlstm_main<<<dim3(16, 64), 256, 0, stream>>>(
        xs, hs, ksw, rsw, t, c0, ktime, out);
}